// Round 1
// baseline (1576.743 us; speedup 1.0000x reference)
//
#include <hip/hip_runtime.h>

// SelectiveSSM (Mamba block): B=2, T=2048, D_MODEL=768, D_INNER=1536, D_STATE=16, D_CONV=4
// R1: correct fp32 pipeline. GEMMs = 128x128 tile, 8x8 microtile, LDS-staged (transposed),
// scan = 16 lanes per (b,d) channel with shuffle reduce over states.

#define BB 2
#define TT 2048
#define DMODEL 768
#define DINNER 1536
#define DSTATE 16
#define MM (BB*TT)   // 4096 rows

// ---------------------------------------------------------------------------
// GEMM (NT): C[m,n] = sum_k A[m,k] * W[n,k]   (A:[M,K] rm, W:[N,K] rm)
// EPI==1: += bias[n], then softplus.
// Requires M%128==0, N%128==0, K%16==0 (true for all three uses).
// ---------------------------------------------------------------------------
template<int EPI>
__global__ __launch_bounds__(256, 2)
void gemm_nt(const float* __restrict__ A, const float* __restrict__ W,
             const float* __restrict__ bias, float* __restrict__ C,
             int K, int ldc)
{
    __shared__ float As[16][132];   // [k][m], +4 pad keeps 16B alignment
    __shared__ float Bs[16][132];   // [k][n]
    const int tid  = threadIdx.x;
    const int mTile = blockIdx.y * 128;
    const int nTile = blockIdx.x * 128;
    const int r  = tid >> 2;          // 0..63 staging row
    const int kc = (tid & 3) << 2;    // 0,4,8,12
    const int ty = tid >> 4;          // 0..15
    const int tx = tid & 15;          // 0..15
    const int m0 = ty * 8;
    const int n0 = tx * 8;

    float acc[8][8];
#pragma unroll
    for (int i = 0; i < 8; ++i)
#pragma unroll
        for (int j = 0; j < 8; ++j) acc[i][j] = 0.f;

    for (int kb = 0; kb < K; kb += 16) {
        __syncthreads();
#pragma unroll
        for (int p = 0; p < 2; ++p) {
            const int row = r + p * 64;
            const float4 av = *(const float4*)&A[(size_t)(mTile + row) * K + kb + kc];
            const float4 wv = *(const float4*)&W[(size_t)(nTile + row) * K + kb + kc];
            As[kc+0][row] = av.x; As[kc+1][row] = av.y; As[kc+2][row] = av.z; As[kc+3][row] = av.w;
            Bs[kc+0][row] = wv.x; Bs[kc+1][row] = wv.y; Bs[kc+2][row] = wv.z; Bs[kc+3][row] = wv.w;
        }
        __syncthreads();
#pragma unroll
        for (int k = 0; k < 16; ++k) {
            const float4 a0 = *(const float4*)&As[k][m0];
            const float4 a1 = *(const float4*)&As[k][m0+4];
            const float4 b0 = *(const float4*)&Bs[k][n0];
            const float4 b1 = *(const float4*)&Bs[k][n0+4];
            const float a8[8] = {a0.x,a0.y,a0.z,a0.w,a1.x,a1.y,a1.z,a1.w};
            const float b8[8] = {b0.x,b0.y,b0.z,b0.w,b1.x,b1.y,b1.z,b1.w};
#pragma unroll
            for (int i = 0; i < 8; ++i)
#pragma unroll
                for (int j = 0; j < 8; ++j)
                    acc[i][j] = fmaf(a8[i], b8[j], acc[i][j]);
        }
    }

#pragma unroll
    for (int i = 0; i < 8; ++i) {
        float* crow = C + (size_t)(mTile + m0 + i) * ldc + nTile + n0;
#pragma unroll
        for (int jq = 0; jq < 2; ++jq) {
            float t4[4];
#pragma unroll
            for (int j = 0; j < 4; ++j) {
                float val = acc[i][jq*4 + j];
                if (EPI == 1) {
                    val += bias[nTile + n0 + jq*4 + j];
                    // softplus, stable: max(x,0) + log1p(exp(-|x|))
                    val = fmaxf(val, 0.f) + log1pf(expf(-fabsf(val)));
                }
                t4[j] = val;
            }
            float4 v; v.x = t4[0]; v.y = t4[1]; v.z = t4[2]; v.w = t4[3];
            *(float4*)&crow[jq*4] = v;
        }
    }
}

// ---------------------------------------------------------------------------
// Depthwise causal conv (width 4) + bias + SiLU.
// in: xz[m*3072 + c] (x_proj half, c<1536) -> xc[m*1536 + c]
// ---------------------------------------------------------------------------
__global__ __launch_bounds__(256)
void conv_silu_kernel(const float* __restrict__ xz, const float4* __restrict__ cw,
                      const float* __restrict__ cb, float* __restrict__ xc)
{
    const int idx = blockIdx.x * 256 + threadIdx.x;  // < 6291456
    const int c = idx % DINNER;
    const int m = idx / DINNER;
    const int t = m & (TT - 1);
    const float4 w = cw[c];
    const size_t p = (size_t)m * (2*DINNER) + c;
    float acc = cb[c];
    if (t >= 3) {
        acc = fmaf(w.x, xz[p - (size_t)3*2*DINNER], acc);
        acc = fmaf(w.y, xz[p - (size_t)2*2*DINNER], acc);
        acc = fmaf(w.z, xz[p - (size_t)1*2*DINNER], acc);
        acc = fmaf(w.w, xz[p], acc);
    } else {
        acc = fmaf(w.w, xz[p], acc);
        if (t >= 1) acc = fmaf(w.z, xz[p - (size_t)1*2*DINNER], acc);
        if (t >= 2) acc = fmaf(w.y, xz[p - (size_t)2*2*DINNER], acc);
    }
    xc[idx] = acc / (1.f + __expf(-acc));   // silu
}

// ---------------------------------------------------------------------------
// Bv[m,n] = sum_d xc[m,d]*B_w[n,d];  Cv likewise. n = idx&31 (<16 -> B, else C).
// ---------------------------------------------------------------------------
__global__ __launch_bounds__(256)
void bc_kernel(const float* __restrict__ xc, const float* __restrict__ Bw,
               const float* __restrict__ Cw, float* __restrict__ Bv, float* __restrict__ Cv)
{
    const int idx = blockIdx.x * 256 + threadIdx.x;  // < 131072
    const int m = idx >> 5;
    const int n = idx & 31;
    const float* __restrict__ w = (n < 16) ? (Bw + (size_t)n * DINNER)
                                           : (Cw + (size_t)(n - 16) * DINNER);
    const float* __restrict__ xr = xc + (size_t)m * DINNER;
    float s = 0.f;
#pragma unroll 4
    for (int d0 = 0; d0 < DINNER; d0 += 4) {
        const float4 a = *(const float4*)&xr[d0];
        const float4 b = *(const float4*)&w[d0];
        s = fmaf(a.x, b.x, s); s = fmaf(a.y, b.y, s);
        s = fmaf(a.z, b.z, s); s = fmaf(a.w, b.w, s);
    }
    if (n < 16) Bv[(size_t)m*DSTATE + n] = s;
    else        Cv[(size_t)m*DSTATE + (n - 16)] = s;
}

// ---------------------------------------------------------------------------
// Selective scan. 16 lanes per (b,d): lane handles state n.
//   h = exp(dt*A_n)*h + (dt*Bv_n)*xc;  y = sum_n h*Cv_n  (shuffle reduce)
// Fused epilogue: y = y*silu(z) + xc*D.
// Prefetches t+1 unconditionally (overruns stay inside d_ws; values unused).
// ---------------------------------------------------------------------------
__global__ __launch_bounds__(256)
void scan_kernel(const float* __restrict__ dt, const float* __restrict__ xc,
                 const float* __restrict__ Bv, const float* __restrict__ Cv,
                 const float* __restrict__ A_log, const float* __restrict__ Dp,
                 const float* __restrict__ xz, float* __restrict__ y)
{
    const int g  = blockIdx.x * 256 + threadIdx.x;  // < 49152
    const int n  = g & 15;
    const int gi = g >> 4;            // channel 0..3071
    const int b  = gi / DINNER;
    const int d  = gi - b * DINNER;
    const float a_n = -__expf(A_log[(size_t)d * DSTATE + n]);
    const float Dv  = Dp[d];
    float h = 0.f;
    size_t m = (size_t)b * TT;
    float dtv = dt[m*DINNER + d];
    float xv  = xc[m*DINNER + d];
    float zv  = xz[m*2*DINNER + DINNER + d];
    float bv  = Bv[m*DSTATE + n];
    float cv  = Cv[m*DSTATE + n];
    for (int t = 0; t < TT; ++t) {
        const size_t m1 = m + 1;
        const float dtv_n = dt[m1*DINNER + d];
        const float xv_n  = xc[m1*DINNER + d];
        const float zv_n  = xz[m1*2*DINNER + DINNER + d];
        const float bv_n  = Bv[m1*DSTATE + n];
        const float cv_n  = Cv[m1*DSTATE + n];

        const float dA = __expf(dtv * a_n);
        h = fmaf(dA, h, dtv * bv * xv);
        float r = h * cv;
        r += __shfl_xor(r, 1);
        r += __shfl_xor(r, 2);
        r += __shfl_xor(r, 4);
        r += __shfl_xor(r, 8);
        if (n == 0) {
            const float sz = zv / (1.f + __expf(-zv));
            y[m*DINNER + d] = fmaf(r, sz, xv * Dv);
        }
        dtv = dtv_n; xv = xv_n; zv = zv_n; bv = bv_n; cv = cv_n;
        m = m1;
    }
}

// ---------------------------------------------------------------------------
// RMSNorm over last dim (768) of (o + x), scaled by norm_w. One block per row.
// ---------------------------------------------------------------------------
__global__ __launch_bounds__(256)
void rmsnorm_kernel(const float* __restrict__ o, const float* __restrict__ x,
                    const float* __restrict__ nw, float* __restrict__ outp)
{
    const int mrow = blockIdx.x;
    const int tid  = threadIdx.x;
    const size_t base = (size_t)mrow * DMODEL;
    const int i0 = tid, i1 = tid + 256, i2 = tid + 512;
    float r0 = o[base+i0] + x[base+i0];
    float r1 = o[base+i1] + x[base+i1];
    float r2 = o[base+i2] + x[base+i2];
    float ss = r0*r0 + r1*r1 + r2*r2;
    ss += __shfl_xor(ss, 1);  ss += __shfl_xor(ss, 2);  ss += __shfl_xor(ss, 4);
    ss += __shfl_xor(ss, 8);  ss += __shfl_xor(ss, 16); ss += __shfl_xor(ss, 32);
    __shared__ float red[4];
    if ((tid & 63) == 0) red[tid >> 6] = ss;
    __syncthreads();
    const float tot = red[0] + red[1] + red[2] + red[3];
    const float sc = rsqrtf(tot * (1.f / (float)DMODEL) + 1e-6f);
    outp[base+i0] = r0 * sc * nw[i0];
    outp[base+i1] = r1 * sc * nw[i1];
    outp[base+i2] = r2 * sc * nw[i2];
}

// ---------------------------------------------------------------------------
extern "C" void kernel_launch(void* const* d_in, const int* in_sizes, int n_in,
                              void* d_out, int out_size, void* d_ws, size_t ws_size,
                              hipStream_t stream)
{
    const float* x         = (const float*)d_in[0];
    const float* in_proj_w = (const float*)d_in[1];
    const float* conv_w    = (const float*)d_in[2];
    const float* conv_b    = (const float*)d_in[3];
    const float* dt_w      = (const float*)d_in[4];
    const float* dt_b      = (const float*)d_in[5];
    const float* A_log     = (const float*)d_in[6];
    const float* B_w       = (const float*)d_in[7];
    const float* C_w       = (const float*)d_in[8];
    const float* D_param   = (const float*)d_in[9];
    const float* out_w     = (const float*)d_in[10];
    const float* norm_w    = (const float*)d_in[11];
    float* out = (float*)d_out;

    // Workspace layout (floats). Total = 31,588,352 floats = 126.4 MB.
    float* ws  = (float*)d_ws;
    float* xz  = ws;                         // [4096][3072]  12,582,912
    float* xc  = xz  + (size_t)MM * 2*DINNER;   // [4096][1536]   6,291,456
    float* dtb = xc  + (size_t)MM * DINNER;     // [4096][1536]   6,291,456
    float* Bv  = dtb + (size_t)MM * DINNER;     // [4096][16]        65,536
    float* Cv  = Bv  + (size_t)MM * DSTATE;     // [4096][16]        65,536
    float* y   = Cv  + (size_t)MM * DSTATE;     // [4096][1536]   6,291,456
    float* o   = xz;                            // reuse xz after scan consumed z

    // 1) xz = x @ in_proj_w^T          (4096 x 3072 x 768)
    gemm_nt<0><<<dim3(2*DINNER/128, MM/128), 256, 0, stream>>>(x, in_proj_w, nullptr, xz, DMODEL, 2*DINNER);
    // 2) xc = silu(causal_conv(x_proj) + conv_b)
    conv_silu_kernel<<<(MM*DINNER)/256, 256, 0, stream>>>(xz, (const float4*)conv_w, conv_b, xc);
    // 3) dt = softplus(xc @ dt_w^T + dt_b)   (4096 x 1536 x 1536)
    gemm_nt<1><<<dim3(DINNER/128, MM/128), 256, 0, stream>>>(xc, dt_w, dt_b, dtb, DINNER, DINNER);
    // 3b) Bv, Cv = xc @ {B_w,C_w}^T    (4096 x 16 x 1536 each)
    bc_kernel<<<(MM*32)/256, 256, 0, stream>>>(xc, B_w, C_w, Bv, Cv);
    // 4) selective scan + gate fuse -> y
    scan_kernel<<<(BB*DINNER*DSTATE)/256, 256, 0, stream>>>(dtb, xc, Bv, Cv, A_log, D_param, xz, y);
    // 5) o = y @ out_w^T               (4096 x 768 x 1536)
    gemm_nt<0><<<dim3(DMODEL/128, MM/128), 256, 0, stream>>>(y, out_w, nullptr, o, DINNER, DMODEL);
    // 6) out = rmsnorm(o + x) * norm_w
    rmsnorm_kernel<<<MM, 256, 0, stream>>>(o, x, norm_w, out);
}

// Round 2
// 1051.824 us; speedup vs baseline: 1.4991x; 1.4991x over previous
//
#include <hip/hip_runtime.h>

// SelectiveSSM (Mamba block): B=2, T=2048, D_MODEL=768, D_INNER=1536, D_STATE=16, D_CONV=4
// R2: chunked parallel scan (3 passes) replaces the 2048-step serial scan.
// GEMMs unchanged (fp32 128x128 tile); bf16 MFMA planned next.

#define BB 2
#define TT 2048
#define DMODEL 768
#define DINNER 1536
#define DSTATE 16
#define MM (BB*TT)   // 4096 rows

#define NC 32            // scan chunks
#define LC (TT/NC)       // 64 steps per chunk
#define GROUPS (BB*DINNER*DSTATE)   // 49152 (b,d,n) recurrences

// ---------------------------------------------------------------------------
// GEMM (NT): C[m,n] = sum_k A[m,k] * W[n,k]   (A:[M,K] rm, W:[N,K] rm)
// EPI==1: += bias[n], then softplus.
// ---------------------------------------------------------------------------
template<int EPI>
__global__ __launch_bounds__(256, 2)
void gemm_nt(const float* __restrict__ A, const float* __restrict__ W,
             const float* __restrict__ bias, float* __restrict__ C,
             int K, int ldc)
{
    __shared__ float As[16][132];
    __shared__ float Bs[16][132];
    const int tid  = threadIdx.x;
    const int mTile = blockIdx.y * 128;
    const int nTile = blockIdx.x * 128;
    const int r  = tid >> 2;
    const int kc = (tid & 3) << 2;
    const int ty = tid >> 4;
    const int tx = tid & 15;
    const int m0 = ty * 8;
    const int n0 = tx * 8;

    float acc[8][8];
#pragma unroll
    for (int i = 0; i < 8; ++i)
#pragma unroll
        for (int j = 0; j < 8; ++j) acc[i][j] = 0.f;

    for (int kb = 0; kb < K; kb += 16) {
        __syncthreads();
#pragma unroll
        for (int p = 0; p < 2; ++p) {
            const int row = r + p * 64;
            const float4 av = *(const float4*)&A[(size_t)(mTile + row) * K + kb + kc];
            const float4 wv = *(const float4*)&W[(size_t)(nTile + row) * K + kb + kc];
            As[kc+0][row] = av.x; As[kc+1][row] = av.y; As[kc+2][row] = av.z; As[kc+3][row] = av.w;
            Bs[kc+0][row] = wv.x; Bs[kc+1][row] = wv.y; Bs[kc+2][row] = wv.z; Bs[kc+3][row] = wv.w;
        }
        __syncthreads();
#pragma unroll
        for (int k = 0; k < 16; ++k) {
            const float4 a0 = *(const float4*)&As[k][m0];
            const float4 a1 = *(const float4*)&As[k][m0+4];
            const float4 b0 = *(const float4*)&Bs[k][n0];
            const float4 b1 = *(const float4*)&Bs[k][n0+4];
            const float a8[8] = {a0.x,a0.y,a0.z,a0.w,a1.x,a1.y,a1.z,a1.w};
            const float b8[8] = {b0.x,b0.y,b0.z,b0.w,b1.x,b1.y,b1.z,b1.w};
#pragma unroll
            for (int i = 0; i < 8; ++i)
#pragma unroll
                for (int j = 0; j < 8; ++j)
                    acc[i][j] = fmaf(a8[i], b8[j], acc[i][j]);
        }
    }

#pragma unroll
    for (int i = 0; i < 8; ++i) {
        float* crow = C + (size_t)(mTile + m0 + i) * ldc + nTile + n0;
#pragma unroll
        for (int jq = 0; jq < 2; ++jq) {
            float t4[4];
#pragma unroll
            for (int j = 0; j < 4; ++j) {
                float val = acc[i][jq*4 + j];
                if (EPI == 1) {
                    val += bias[nTile + n0 + jq*4 + j];
                    val = fmaxf(val, 0.f) + log1pf(expf(-fabsf(val)));
                }
                t4[j] = val;
            }
            float4 v; v.x = t4[0]; v.y = t4[1]; v.z = t4[2]; v.w = t4[3];
            *(float4*)&crow[jq*4] = v;
        }
    }
}

// ---------------------------------------------------------------------------
// Depthwise causal conv (width 4) + bias + SiLU.
// ---------------------------------------------------------------------------
__global__ __launch_bounds__(256)
void conv_silu_kernel(const float* __restrict__ xz, const float4* __restrict__ cw,
                      const float* __restrict__ cb, float* __restrict__ xc)
{
    const int idx = blockIdx.x * 256 + threadIdx.x;
    const int c = idx % DINNER;
    const int m = idx / DINNER;
    const int t = m & (TT - 1);
    const float4 w = cw[c];
    const size_t p = (size_t)m * (2*DINNER) + c;
    float acc = cb[c];
    if (t >= 3) {
        acc = fmaf(w.x, xz[p - (size_t)3*2*DINNER], acc);
        acc = fmaf(w.y, xz[p - (size_t)2*2*DINNER], acc);
        acc = fmaf(w.z, xz[p - (size_t)1*2*DINNER], acc);
        acc = fmaf(w.w, xz[p], acc);
    } else {
        acc = fmaf(w.w, xz[p], acc);
        if (t >= 1) acc = fmaf(w.z, xz[p - (size_t)1*2*DINNER], acc);
        if (t >= 2) acc = fmaf(w.y, xz[p - (size_t)2*2*DINNER], acc);
    }
    xc[idx] = acc / (1.f + __expf(-acc));
}

// ---------------------------------------------------------------------------
// Bv[m,n] = sum_d xc[m,d]*B_w[n,d];  Cv likewise.
// ---------------------------------------------------------------------------
__global__ __launch_bounds__(256)
void bc_kernel(const float* __restrict__ xc, const float* __restrict__ Bw,
               const float* __restrict__ Cw, float* __restrict__ Bv, float* __restrict__ Cv)
{
    const int idx = blockIdx.x * 256 + threadIdx.x;
    const int m = idx >> 5;
    const int n = idx & 31;
    const float* __restrict__ w = (n < 16) ? (Bw + (size_t)n * DINNER)
                                           : (Cw + (size_t)(n - 16) * DINNER);
    const float* __restrict__ xr = xc + (size_t)m * DINNER;
    float s = 0.f;
#pragma unroll 4
    for (int d0 = 0; d0 < DINNER; d0 += 4) {
        const float4 a = *(const float4*)&xr[d0];
        const float4 b = *(const float4*)&w[d0];
        s = fmaf(a.x, b.x, s); s = fmaf(a.y, b.y, s);
        s = fmaf(a.z, b.z, s); s = fmaf(a.w, b.w, s);
    }
    if (n < 16) Bv[(size_t)m*DSTATE + n] = s;
    else        Cv[(size_t)m*DSTATE + (n - 16)] = s;
}

// ---------------------------------------------------------------------------
// Chunked scan, pass 1: per (chunk c, b, d, n) compute
//   P = prod_t dA_t   and   S = local h (h_in = 0) over the chunk.
// Thread g = ((c*BB + b)*DINNER + d)*16 + n, so P/S are [c][(b,d,n)] flat.
// ---------------------------------------------------------------------------
__global__ __launch_bounds__(256)
void scan_pass1(const float* __restrict__ dt, const float* __restrict__ xc,
                const float* __restrict__ Bv, const float* __restrict__ A_log,
                float* __restrict__ P, float* __restrict__ S)
{
    const int g = blockIdx.x * 256 + threadIdx.x;   // < GROUPS*NC
    const int n    = g & 15;
    const int rest = g >> 4;
    const int d    = rest % DINNER;
    const int cb   = rest / DINNER;
    const int b    = cb & (BB - 1);
    const int c    = cb >> 1;
    const float a_n = -__expf(A_log[(size_t)d * DSTATE + n]);
    float h = 0.f, p = 1.f;
    const size_t m = (size_t)b * TT + (size_t)c * LC;
    const float* __restrict__ dtp = dt + m * DINNER + d;
    const float* __restrict__ xcp = xc + m * DINNER + d;
    const float* __restrict__ bvp = Bv + m * DSTATE + n;
#pragma unroll 4
    for (int t = 0; t < LC; ++t) {
        const float dtv = dtp[(size_t)t * DINNER];
        const float xv  = xcp[(size_t)t * DINNER];
        const float bv  = bvp[(size_t)t * DSTATE];
        const float dA  = __expf(dtv * a_n);
        p *= dA;
        h = fmaf(dA, h, dtv * bv * xv);
    }
    P[g] = p;
    S[g] = h;
}

// ---------------------------------------------------------------------------
// Chunked scan, pass 2: sequential combine over the NC chunks.
// In-place: PH[c][j] (was P) is overwritten with h_in for chunk c.
//   h_in[0]=0; h_in[c] = P[c-1]*h_in[c-1] + S[c-1]
// ---------------------------------------------------------------------------
__global__ __launch_bounds__(256)
void scan_combine(float* __restrict__ PH, const float* __restrict__ S)
{
    const int j = blockIdx.x * 256 + threadIdx.x;   // < GROUPS
    float h = 0.f;
#pragma unroll
    for (int c = 0; c < NC; ++c) {
        const size_t o = (size_t)c * GROUPS + j;
        const float p = PH[o];
        const float s = S[o];
        PH[o] = h;
        h = fmaf(p, h, s);
    }
}

// ---------------------------------------------------------------------------
// Chunked scan, pass 3: re-run each chunk from its exact h_in, emit
//   y = (h·C) * silu(z) + xc * D   (shuffle reduce over the 16 states)
// ---------------------------------------------------------------------------
__global__ __launch_bounds__(256)
void scan_pass3(const float* __restrict__ dt, const float* __restrict__ xc,
                const float* __restrict__ Bv, const float* __restrict__ Cv,
                const float* __restrict__ A_log, const float* __restrict__ Dp,
                const float* __restrict__ xz, const float* __restrict__ H0,
                float* __restrict__ y)
{
    const int g = blockIdx.x * 256 + threadIdx.x;   // < GROUPS*NC
    const int n    = g & 15;
    const int rest = g >> 4;
    const int d    = rest % DINNER;
    const int cb   = rest / DINNER;
    const int b    = cb & (BB - 1);
    const int c    = cb >> 1;
    const float a_n = -__expf(A_log[(size_t)d * DSTATE + n]);
    const float Dv  = Dp[d];
    float h = H0[g];
    const size_t m0 = (size_t)b * TT + (size_t)c * LC;
    const float* __restrict__ dtp = dt + m0 * DINNER + d;
    const float* __restrict__ xcp = xc + m0 * DINNER + d;
    const float* __restrict__ zp  = xz + m0 * (2*DINNER) + DINNER + d;
    const float* __restrict__ bvp = Bv + m0 * DSTATE + n;
    const float* __restrict__ cvp = Cv + m0 * DSTATE + n;
    float* __restrict__ yp = y + m0 * DINNER + d;
#pragma unroll 2
    for (int t = 0; t < LC; ++t) {
        const float dtv = dtp[(size_t)t * DINNER];
        const float xv  = xcp[(size_t)t * DINNER];
        const float zv  = zp [(size_t)t * (2*DINNER)];
        const float bv  = bvp[(size_t)t * DSTATE];
        const float cv  = cvp[(size_t)t * DSTATE];
        const float dA  = __expf(dtv * a_n);
        h = fmaf(dA, h, dtv * bv * xv);
        float r = h * cv;
        r += __shfl_xor(r, 1);
        r += __shfl_xor(r, 2);
        r += __shfl_xor(r, 4);
        r += __shfl_xor(r, 8);
        if (n == 0) {
            const float sz = zv / (1.f + __expf(-zv));
            yp[(size_t)t * DINNER] = fmaf(r, sz, xv * Dv);
        }
    }
}

// ---------------------------------------------------------------------------
// RMSNorm over last dim (768) of (o + x), scaled by norm_w.
// ---------------------------------------------------------------------------
__global__ __launch_bounds__(256)
void rmsnorm_kernel(const float* __restrict__ o, const float* __restrict__ x,
                    const float* __restrict__ nw, float* __restrict__ outp)
{
    const int mrow = blockIdx.x;
    const int tid  = threadIdx.x;
    const size_t base = (size_t)mrow * DMODEL;
    const int i0 = tid, i1 = tid + 256, i2 = tid + 512;
    float r0 = o[base+i0] + x[base+i0];
    float r1 = o[base+i1] + x[base+i1];
    float r2 = o[base+i2] + x[base+i2];
    float ss = r0*r0 + r1*r1 + r2*r2;
    ss += __shfl_xor(ss, 1);  ss += __shfl_xor(ss, 2);  ss += __shfl_xor(ss, 4);
    ss += __shfl_xor(ss, 8);  ss += __shfl_xor(ss, 16); ss += __shfl_xor(ss, 32);
    __shared__ float red[4];
    if ((tid & 63) == 0) red[tid >> 6] = ss;
    __syncthreads();
    const float tot = red[0] + red[1] + red[2] + red[3];
    const float sc = rsqrtf(tot * (1.f / (float)DMODEL) + 1e-6f);
    outp[base+i0] = r0 * sc * nw[i0];
    outp[base+i1] = r1 * sc * nw[i1];
    outp[base+i2] = r2 * sc * nw[i2];
}

// ---------------------------------------------------------------------------
extern "C" void kernel_launch(void* const* d_in, const int* in_sizes, int n_in,
                              void* d_out, int out_size, void* d_ws, size_t ws_size,
                              hipStream_t stream)
{
    const float* x         = (const float*)d_in[0];
    const float* in_proj_w = (const float*)d_in[1];
    const float* conv_w    = (const float*)d_in[2];
    const float* conv_b    = (const float*)d_in[3];
    const float* dt_w      = (const float*)d_in[4];
    const float* dt_b      = (const float*)d_in[5];
    const float* A_log     = (const float*)d_in[6];
    const float* B_w       = (const float*)d_in[7];
    const float* C_w       = (const float*)d_in[8];
    const float* D_param   = (const float*)d_in[9];
    const float* out_w     = (const float*)d_in[10];
    const float* norm_w    = (const float*)d_in[11];
    float* out = (float*)d_out;

    // Workspace layout (floats). Total = 34,734,080 floats = 138.9 MB.
    float* ws  = (float*)d_ws;
    float* xz  = ws;                              // [4096][3072]  12,582,912
    float* xc  = xz  + (size_t)MM * 2*DINNER;     // [4096][1536]   6,291,456
    float* dtb = xc  + (size_t)MM * DINNER;       // [4096][1536]   6,291,456
    float* Bv  = dtb + (size_t)MM * DINNER;       // [4096][16]        65,536
    float* Cv  = Bv  + (size_t)MM * DSTATE;       // [4096][16]        65,536
    float* y   = Cv  + (size_t)MM * DSTATE;       // [4096][1536]   6,291,456
    float* Pa  = y   + (size_t)MM * DINNER;       // [NC][GROUPS]   1,572,864 (h0 overlays)
    float* Sa  = Pa  + (size_t)NC * GROUPS;       // [NC][GROUPS]   1,572,864
    float* o   = xz;                              // reuse xz after scan consumed z

    // 1) xz = x @ in_proj_w^T          (4096 x 3072 x 768)
    gemm_nt<0><<<dim3(2*DINNER/128, MM/128), 256, 0, stream>>>(x, in_proj_w, nullptr, xz, DMODEL, 2*DINNER);
    // 2) xc = silu(causal_conv(x_proj) + conv_b)
    conv_silu_kernel<<<(MM*DINNER)/256, 256, 0, stream>>>(xz, (const float4*)conv_w, conv_b, xc);
    // 3) dt = softplus(xc @ dt_w^T + dt_b)   (4096 x 1536 x 1536)
    gemm_nt<1><<<dim3(DINNER/128, MM/128), 256, 0, stream>>>(xc, dt_w, dt_b, dtb, DINNER, DINNER);
    // 3b) Bv, Cv = xc @ {B_w,C_w}^T
    bc_kernel<<<(MM*32)/256, 256, 0, stream>>>(xc, B_w, C_w, Bv, Cv);
    // 4) chunked selective scan
    scan_pass1<<<(GROUPS*NC)/256, 256, 0, stream>>>(dtb, xc, Bv, A_log, Pa, Sa);
    scan_combine<<<GROUPS/256, 256, 0, stream>>>(Pa, Sa);
    scan_pass3<<<(GROUPS*NC)/256, 256, 0, stream>>>(dtb, xc, Bv, Cv, A_log, D_param, xz, Pa, y);
    // 5) o = y @ out_w^T               (4096 x 768 x 1536)
    gemm_nt<0><<<dim3(DMODEL/128, MM/128), 256, 0, stream>>>(y, out_w, nullptr, o, DINNER, DMODEL);
    // 6) out = rmsnorm(o + x) * norm_w
    rmsnorm_kernel<<<MM, 256, 0, stream>>>(o, x, norm_w, out);
}

// Round 3
// 474.719 us; speedup vs baseline: 3.3214x; 2.2157x over previous
//
#include <hip/hip_runtime.h>

// SelectiveSSM (Mamba block): B=2, T=2048, D_MODEL=768, D_INNER=1536, D_STATE=16, D_CONV=4
// R3: bf16 MFMA GEMMs (m97 structure: 128x128 tile, BK=64, global_load_lds w16,
//     mfma_f32_16x16x32_bf16 4x4 frags/wave). Chunked scan kept (fp32 math, bf16 xc/y).

#define BB 2
#define TT 2048
#define DMODEL 768
#define DINNER 1536
#define DSTATE 16
#define MM (BB*TT)   // 4096 rows

#define NC 32
#define LC (TT/NC)
#define GROUPS (BB*DINNER*DSTATE)   // 49152

typedef __attribute__((ext_vector_type(8))) short bf16x8;
typedef __attribute__((ext_vector_type(4))) float f32x4;
typedef __attribute__((ext_vector_type(8))) short short8;

__device__ inline float bf2f(short u) {
    union { unsigned int i; float f; } v;
    v.i = ((unsigned int)(unsigned short)u) << 16;
    return v.f;
}
__device__ inline short f2bf(float f) {   // round-to-nearest-even
    unsigned int u = __float_as_uint(f);
    u = (u + 0x7fffu + ((u >> 16) & 1u)) >> 16;
    return (short)u;
}

// ---------------------------------------------------------------------------
// Fused fp32->bf16 pack: x, in_proj_w, dt_w, out_w. 8 elems/thread.
// ---------------------------------------------------------------------------
#define S0 (MM*DMODEL)          // x        3,145,728
#define S1 (2*DINNER*DMODEL)    // in_proj  2,359,296
#define S2 (DINNER*DINNER)      // dt_w     2,359,296
#define S3 (DMODEL*DINNER)      // out_w    1,179,648
#define TOTC (S0+S1+S2+S3)      //          9,043,968

__global__ __launch_bounds__(256)
void cvt_pack(const float* __restrict__ x, const float* __restrict__ w1,
              const float* __restrict__ w2, const float* __restrict__ w3,
              short* __restrict__ xb, short* __restrict__ b1,
              short* __restrict__ b2, short* __restrict__ b3)
{
    const size_t i8 = ((size_t)blockIdx.x * 256 + threadIdx.x) * 8;
    const float* src; short* dst; size_t off;
    if (i8 < S0)            { src = x;  dst = xb; off = i8; }
    else if (i8 < S0+S1)    { src = w1; dst = b1; off = i8 - S0; }
    else if (i8 < S0+S1+S2) { src = w2; dst = b2; off = i8 - (S0+S1); }
    else                    { src = w3; dst = b3; off = i8 - (S0+S1+S2); }
    const float4 a = *(const float4*)(src + off);
    const float4 b = *(const float4*)(src + off + 4);
    short8 o;
    o[0]=f2bf(a.x); o[1]=f2bf(a.y); o[2]=f2bf(a.z); o[3]=f2bf(a.w);
    o[4]=f2bf(b.x); o[5]=f2bf(b.y); o[6]=f2bf(b.z); o[7]=f2bf(b.w);
    *(short8*)(dst + off) = o;
}

// ---------------------------------------------------------------------------
// bf16 MFMA GEMM (NT): C[m,n] = sum_k A[m,k]*W[n,k], fp32 out.
// A:[M][K] bf16 rm, W:[N][K] bf16 rm. M%128==0, N%128==0, K%64==0.
// EPI==1: += bias[n] then softplus.
// m97 structure: 128x128 tile, BK=64, 4 waves -> 64x64 each (4x4 16x16 frags).
// ---------------------------------------------------------------------------
template<int EPI>
__global__ __launch_bounds__(256)
void gemm_bf16(const short* __restrict__ A, const short* __restrict__ W,
               const float* __restrict__ bias, float* __restrict__ C,
               int K, int ldc)
{
    __shared__ short As[128*64];
    __shared__ short Bs[128*64];
    const int tid = threadIdx.x;
    const int w = tid >> 6, l = tid & 63;
    const int mTile = blockIdx.y * 128, nTile = blockIdx.x * 128;
    const int wr = w >> 1, wc = w & 1;
    const int srow = l >> 3;          // 0..7
    const int scol = (l & 7) * 8;     // 0..56 bf16

    f32x4 acc[4][4];
#pragma unroll
    for (int i = 0; i < 4; ++i)
#pragma unroll
        for (int j = 0; j < 4; ++j) acc[i][j] = (f32x4)0.f;

    for (int kb = 0; kb < K; kb += 64) {
        __syncthreads();
#pragma unroll
        for (int j = 0; j < 4; ++j) {
            const int row = (j*4 + w)*8 + srow;
            __builtin_amdgcn_global_load_lds(
                (const __attribute__((address_space(1))) void*)(A + (size_t)(mTile+row)*K + kb + scol),
                (__attribute__((address_space(3))) void*)(As + row*64 + scol), 16, 0, 0);
            __builtin_amdgcn_global_load_lds(
                (const __attribute__((address_space(1))) void*)(W + (size_t)(nTile+row)*K + kb + scol),
                (__attribute__((address_space(3))) void*)(Bs + row*64 + scol), 16, 0, 0);
        }
        __syncthreads();   // compiler inserts vmcnt(0) drain before barrier
#pragma unroll
        for (int kk = 0; kk < 2; ++kk) {
            bf16x8 af[4], bfr[4];
#pragma unroll
            for (int i = 0; i < 4; ++i) {
                af [i] = *(const bf16x8*)&As[(wr*64 + i*16 + (l&15))*64 + kk*32 + (l>>4)*8];
                bfr[i] = *(const bf16x8*)&Bs[(wc*64 + i*16 + (l&15))*64 + kk*32 + (l>>4)*8];
            }
#pragma unroll
            for (int i = 0; i < 4; ++i)
#pragma unroll
                for (int jf = 0; jf < 4; ++jf)
                    acc[i][jf] = __builtin_amdgcn_mfma_f32_16x16x32_bf16(af[i], bfr[jf], acc[i][jf], 0, 0, 0);
        }
    }

    // C/D layout (m89-verified): col = lane&15, row = (lane>>4)*4 + reg
#pragma unroll
    for (int i = 0; i < 4; ++i) {
        const int mbase = mTile + wr*64 + i*16 + (l >> 4)*4;
#pragma unroll
        for (int jf = 0; jf < 4; ++jf) {
            const int n = nTile + wc*64 + jf*16 + (l & 15);
            float bv = (EPI == 1) ? bias[n] : 0.f;
#pragma unroll
            for (int r = 0; r < 4; ++r) {
                float v = acc[i][jf][r];
                if (EPI == 1) {
                    v += bv;
                    v = fmaxf(v, 0.f) + log1pf(expf(-fabsf(v)));   // softplus
                }
                C[(size_t)(mbase + r)*ldc + n] = v;
            }
        }
    }
}

// ---------------------------------------------------------------------------
// Depthwise causal conv (width 4) + bias + SiLU -> bf16 xc.
// ---------------------------------------------------------------------------
__global__ __launch_bounds__(256)
void conv_silu_kernel(const float* __restrict__ xz, const float4* __restrict__ cw,
                      const float* __restrict__ cb, short* __restrict__ xcb)
{
    const int idx = blockIdx.x * 256 + threadIdx.x;
    const int c = idx % DINNER;
    const int m = idx / DINNER;
    const int t = m & (TT - 1);
    const float4 w = cw[c];
    const size_t p = (size_t)m * (2*DINNER) + c;
    float acc = cb[c];
    if (t >= 3) {
        acc = fmaf(w.x, xz[p - (size_t)3*2*DINNER], acc);
        acc = fmaf(w.y, xz[p - (size_t)2*2*DINNER], acc);
        acc = fmaf(w.z, xz[p - (size_t)1*2*DINNER], acc);
        acc = fmaf(w.w, xz[p], acc);
    } else {
        acc = fmaf(w.w, xz[p], acc);
        if (t >= 1) acc = fmaf(w.z, xz[p - (size_t)1*2*DINNER], acc);
        if (t >= 2) acc = fmaf(w.y, xz[p - (size_t)2*2*DINNER], acc);
    }
    xcb[idx] = f2bf(acc / (1.f + __expf(-acc)));
}

// ---------------------------------------------------------------------------
// Bv[m,n] = sum_d xc[m,d]*B_w[n,d];  Cv likewise. xc in bf16.
// ---------------------------------------------------------------------------
__global__ __launch_bounds__(256)
void bc_kernel(const short* __restrict__ xcb, const float* __restrict__ Bw,
               const float* __restrict__ Cw, float* __restrict__ Bv, float* __restrict__ Cv)
{
    const int idx = blockIdx.x * 256 + threadIdx.x;
    const int m = idx >> 5;
    const int n = idx & 31;
    const float* __restrict__ w = (n < 16) ? (Bw + (size_t)n * DINNER)
                                           : (Cw + (size_t)(n - 16) * DINNER);
    const short* __restrict__ xr = xcb + (size_t)m * DINNER;
    float s = 0.f;
#pragma unroll 2
    for (int d0 = 0; d0 < DINNER; d0 += 8) {
        const short8 a = *(const short8*)&xr[d0];
        const float4 b0 = *(const float4*)&w[d0];
        const float4 b1 = *(const float4*)&w[d0+4];
        s = fmaf(bf2f(a[0]), b0.x, s); s = fmaf(bf2f(a[1]), b0.y, s);
        s = fmaf(bf2f(a[2]), b0.z, s); s = fmaf(bf2f(a[3]), b0.w, s);
        s = fmaf(bf2f(a[4]), b1.x, s); s = fmaf(bf2f(a[5]), b1.y, s);
        s = fmaf(bf2f(a[6]), b1.z, s); s = fmaf(bf2f(a[7]), b1.w, s);
    }
    if (n < 16) Bv[(size_t)m*DSTATE + n] = s;
    else        Cv[(size_t)m*DSTATE + (n - 16)] = s;
}

// ---------------------------------------------------------------------------
// Chunked scan pass 1: per (chunk,b,d,n): P = prod dA, S = local h (h_in=0).
// ---------------------------------------------------------------------------
__global__ __launch_bounds__(256)
void scan_pass1(const float* __restrict__ dt, const short* __restrict__ xcb,
                const float* __restrict__ Bv, const float* __restrict__ A_log,
                float* __restrict__ P, float* __restrict__ S)
{
    const int g = blockIdx.x * 256 + threadIdx.x;   // < GROUPS*NC
    const int n    = g & 15;
    const int rest = g >> 4;
    const int d    = rest % DINNER;
    const int cb   = rest / DINNER;
    const int b    = cb & (BB - 1);
    const int c    = cb >> 1;
    const float a_n = -__expf(A_log[(size_t)d * DSTATE + n]);
    float h = 0.f, p = 1.f;
    const size_t m = (size_t)b * TT + (size_t)c * LC;
    const float* __restrict__ dtp = dt  + m * DINNER + d;
    const short* __restrict__ xcp = xcb + m * DINNER + d;
    const float* __restrict__ bvp = Bv  + m * DSTATE + n;
#pragma unroll 4
    for (int t = 0; t < LC; ++t) {
        const float dtv = dtp[(size_t)t * DINNER];
        const float xv  = bf2f(xcp[(size_t)t * DINNER]);
        const float bv  = bvp[(size_t)t * DSTATE];
        const float dA  = __expf(dtv * a_n);
        p *= dA;
        h = fmaf(dA, h, dtv * bv * xv);
    }
    P[g] = p;
    S[g] = h;
}

// ---------------------------------------------------------------------------
// Chunked scan pass 2: sequential combine; PH[c][j] <- h_in for chunk c.
// ---------------------------------------------------------------------------
__global__ __launch_bounds__(256)
void scan_combine(float* __restrict__ PH, const float* __restrict__ S)
{
    const int j = blockIdx.x * 256 + threadIdx.x;   // < GROUPS
    float h = 0.f;
#pragma unroll
    for (int c = 0; c < NC; ++c) {
        const size_t o = (size_t)c * GROUPS + j;
        const float p = PH[o];
        const float s = S[o];
        PH[o] = h;
        h = fmaf(p, h, s);
    }
}

// ---------------------------------------------------------------------------
// Chunked scan pass 3: from exact h_in emit y = (h.C)*silu(z) + xc*D (bf16).
// ---------------------------------------------------------------------------
__global__ __launch_bounds__(256)
void scan_pass3(const float* __restrict__ dt, const short* __restrict__ xcb,
                const float* __restrict__ Bv, const float* __restrict__ Cv,
                const float* __restrict__ A_log, const float* __restrict__ Dp,
                const float* __restrict__ xz, const float* __restrict__ H0,
                short* __restrict__ yb)
{
    const int g = blockIdx.x * 256 + threadIdx.x;   // < GROUPS*NC
    const int n    = g & 15;
    const int rest = g >> 4;
    const int d    = rest % DINNER;
    const int cb   = rest / DINNER;
    const int b    = cb & (BB - 1);
    const int c    = cb >> 1;
    const float a_n = -__expf(A_log[(size_t)d * DSTATE + n]);
    const float Dv  = Dp[d];
    float h = H0[g];
    const size_t m0 = (size_t)b * TT + (size_t)c * LC;
    const float* __restrict__ dtp = dt  + m0 * DINNER + d;
    const short* __restrict__ xcp = xcb + m0 * DINNER + d;
    const float* __restrict__ zp  = xz  + m0 * (2*DINNER) + DINNER + d;
    const float* __restrict__ bvp = Bv  + m0 * DSTATE + n;
    const float* __restrict__ cvp = Cv  + m0 * DSTATE + n;
    short* __restrict__ yp = yb + m0 * DINNER + d;
#pragma unroll 2
    for (int t = 0; t < LC; ++t) {
        const float dtv = dtp[(size_t)t * DINNER];
        const float xv  = bf2f(xcp[(size_t)t * DINNER]);
        const float zv  = zp [(size_t)t * (2*DINNER)];
        const float bv  = bvp[(size_t)t * DSTATE];
        const float cv  = cvp[(size_t)t * DSTATE];
        const float dA  = __expf(dtv * a_n);
        h = fmaf(dA, h, dtv * bv * xv);
        float r = h * cv;
        r += __shfl_xor(r, 1);
        r += __shfl_xor(r, 2);
        r += __shfl_xor(r, 4);
        r += __shfl_xor(r, 8);
        if (n == 0) {
            const float sz = zv / (1.f + __expf(-zv));
            yp[(size_t)t * DINNER] = f2bf(fmaf(r, sz, xv * Dv));
        }
    }
}

// ---------------------------------------------------------------------------
// RMSNorm over last dim (768) of (o + x), scaled by norm_w.
// ---------------------------------------------------------------------------
__global__ __launch_bounds__(256)
void rmsnorm_kernel(const float* __restrict__ o, const float* __restrict__ x,
                    const float* __restrict__ nw, float* __restrict__ outp)
{
    const int mrow = blockIdx.x;
    const int tid  = threadIdx.x;
    const size_t base = (size_t)mrow * DMODEL;
    const int i0 = tid, i1 = tid + 256, i2 = tid + 512;
    float r0 = o[base+i0] + x[base+i0];
    float r1 = o[base+i1] + x[base+i1];
    float r2 = o[base+i2] + x[base+i2];
    float ss = r0*r0 + r1*r1 + r2*r2;
    ss += __shfl_xor(ss, 1);  ss += __shfl_xor(ss, 2);  ss += __shfl_xor(ss, 4);
    ss += __shfl_xor(ss, 8);  ss += __shfl_xor(ss, 16); ss += __shfl_xor(ss, 32);
    __shared__ float red[4];
    if ((tid & 63) == 0) red[tid >> 6] = ss;
    __syncthreads();
    const float tot = red[0] + red[1] + red[2] + red[3];
    const float sc = rsqrtf(tot * (1.f / (float)DMODEL) + 1e-6f);
    outp[base+i0] = r0 * sc * nw[i0];
    outp[base+i1] = r1 * sc * nw[i1];
    outp[base+i2] = r2 * sc * nw[i2];
}

// ---------------------------------------------------------------------------
extern "C" void kernel_launch(void* const* d_in, const int* in_sizes, int n_in,
                              void* d_out, int out_size, void* d_ws, size_t ws_size,
                              hipStream_t stream)
{
    const float* x         = (const float*)d_in[0];
    const float* in_proj_w = (const float*)d_in[1];
    const float* conv_w    = (const float*)d_in[2];
    const float* conv_b    = (const float*)d_in[3];
    const float* dt_w      = (const float*)d_in[4];
    const float* dt_b      = (const float*)d_in[5];
    const float* A_log     = (const float*)d_in[6];
    const float* B_w       = (const float*)d_in[7];
    const float* C_w       = (const float*)d_in[8];
    const float* D_param   = (const float*)d_in[9];
    const float* out_w     = (const float*)d_in[10];
    const float* norm_w    = (const float*)d_in[11];
    float* out = (float*)d_out;

    // ---- workspace layout: fp32 region then bf16 region (total ~131.9 MB) ----
    float* ws  = (float*)d_ws;
    float* xz  = ws;                               // [4096][3072]  12,582,912 f
    float* dtb = xz  + (size_t)MM * 2*DINNER;      // [4096][1536]   6,291,456 f
    float* Bv  = dtb + (size_t)MM * DINNER;        // [4096][16]        65,536 f
    float* Cv  = Bv  + (size_t)MM * DSTATE;        // [4096][16]        65,536 f
    float* Pa  = Cv  + (size_t)MM * DSTATE;        // [NC][GROUPS]   1,572,864 f
    float* Sa  = Pa  + (size_t)NC * GROUPS;        // [NC][GROUPS]   1,572,864 f
    short* bfb = (short*)(Sa + (size_t)NC * GROUPS);
    short* xb  = bfb;                              // x bf16        3,145,728 s
    short* wib = xb  + (size_t)S0;                 // in_proj bf16  2,359,296 s
    short* wdb = wib + (size_t)S1;                 // dt_w bf16     2,359,296 s
    short* wob = wdb + (size_t)S2;                 // out_w bf16    1,179,648 s
    short* xcb = wob + (size_t)S3;                 // xc bf16       6,291,456 s
    short* yb  = xcb + (size_t)MM * DINNER;        // y bf16        6,291,456 s
    float* o   = xz;                               // out-proj result reuses xz

    // 0) pack fp32 -> bf16 (x + 3 weight matrices)
    cvt_pack<<<TOTC/8/256, 256, 0, stream>>>(x, in_proj_w, dt_w, out_w, xb, wib, wdb, wob);
    // 1) xz = x @ in_proj_w^T          (4096 x 3072 x 768, bf16 MFMA)
    gemm_bf16<0><<<dim3(2*DINNER/128, MM/128), 256, 0, stream>>>(xb, wib, nullptr, xz, DMODEL, 2*DINNER);
    // 2) xc = silu(causal_conv(x_proj) + conv_b)  -> bf16
    conv_silu_kernel<<<(MM*DINNER)/256, 256, 0, stream>>>(xz, (const float4*)conv_w, conv_b, xcb);
    // 3) dt = softplus(xc @ dt_w^T + dt_b)   (4096 x 1536 x 1536, bf16 MFMA)
    gemm_bf16<1><<<dim3(DINNER/128, MM/128), 256, 0, stream>>>(xcb, wdb, dt_b, dtb, DINNER, DINNER);
    // 3b) Bv, Cv = xc @ {B_w,C_w}^T
    bc_kernel<<<(MM*32)/256, 256, 0, stream>>>(xcb, B_w, C_w, Bv, Cv);
    // 4) chunked selective scan
    scan_pass1<<<(GROUPS*NC)/256, 256, 0, stream>>>(dtb, xcb, Bv, A_log, Pa, Sa);
    scan_combine<<<GROUPS/256, 256, 0, stream>>>(Pa, Sa);
    scan_pass3<<<(GROUPS*NC)/256, 256, 0, stream>>>(dtb, xcb, Bv, Cv, A_log, D_param, xz, Pa, yb);
    // 5) o = y @ out_w^T               (4096 x 768 x 1536, bf16 MFMA)
    gemm_bf16<0><<<dim3(DMODEL/128, MM/128), 256, 0, stream>>>(yb, wob, nullptr, o, DINNER, DMODEL);
    // 6) out = rmsnorm(o + x) * norm_w
    rmsnorm_kernel<<<MM, 256, 0, stream>>>(o, x, norm_w, out);
}

// Round 4
// 342.104 us; speedup vs baseline: 4.6090x; 1.3876x over previous
//
#include <hip/hip_runtime.h>

// SelectiveSSM (Mamba block): B=2, T=2048, D_MODEL=768, D_INNER=1536, D_STATE=16, D_CONV=4
// R4: scan restructured — one thread per (chunk,b,d) channel, 16 states in registers,
//     no shuffles, Bv/Cv staged in LDS (broadcast reads). NC 32->64.
// GEMMs unchanged from R3 (bf16 MFMA, m97 structure).

#define BB 2
#define TT 2048
#define DMODEL 768
#define DINNER 1536
#define DSTATE 16
#define MM (BB*TT)   // 4096 rows

#define NC 64
#define LC (TT/NC)   // 32 steps per chunk
#define GROUPS (BB*DINNER*DSTATE)   // 49152
#define DBLK (DINNER/256)           // 6 blocks per (c,b)

typedef __attribute__((ext_vector_type(8))) short bf16x8;
typedef __attribute__((ext_vector_type(4))) float f32x4;
typedef __attribute__((ext_vector_type(8))) short short8;

__device__ inline float bf2f(short u) {
    union { unsigned int i; float f; } v;
    v.i = ((unsigned int)(unsigned short)u) << 16;
    return v.f;
}
__device__ inline short f2bf(float f) {   // round-to-nearest-even
    unsigned int u = __float_as_uint(f);
    u = (u + 0x7fffu + ((u >> 16) & 1u)) >> 16;
    return (short)u;
}

// ---------------------------------------------------------------------------
// Fused fp32->bf16 pack: x, in_proj_w, dt_w, out_w. 8 elems/thread.
// ---------------------------------------------------------------------------
#define S0 (MM*DMODEL)          // x        3,145,728
#define S1 (2*DINNER*DMODEL)    // in_proj  2,359,296
#define S2 (DINNER*DINNER)      // dt_w     2,359,296
#define S3 (DMODEL*DINNER)      // out_w    1,179,648
#define TOTC (S0+S1+S2+S3)      //          9,043,968

__global__ __launch_bounds__(256)
void cvt_pack(const float* __restrict__ x, const float* __restrict__ w1,
              const float* __restrict__ w2, const float* __restrict__ w3,
              short* __restrict__ xb, short* __restrict__ b1,
              short* __restrict__ b2, short* __restrict__ b3)
{
    const size_t i8 = ((size_t)blockIdx.x * 256 + threadIdx.x) * 8;
    const float* src; short* dst; size_t off;
    if (i8 < S0)            { src = x;  dst = xb; off = i8; }
    else if (i8 < S0+S1)    { src = w1; dst = b1; off = i8 - S0; }
    else if (i8 < S0+S1+S2) { src = w2; dst = b2; off = i8 - (S0+S1); }
    else                    { src = w3; dst = b3; off = i8 - (S0+S1+S2); }
    const float4 a = *(const float4*)(src + off);
    const float4 b = *(const float4*)(src + off + 4);
    short8 o;
    o[0]=f2bf(a.x); o[1]=f2bf(a.y); o[2]=f2bf(a.z); o[3]=f2bf(a.w);
    o[4]=f2bf(b.x); o[5]=f2bf(b.y); o[6]=f2bf(b.z); o[7]=f2bf(b.w);
    *(short8*)(dst + off) = o;
}

// ---------------------------------------------------------------------------
// bf16 MFMA GEMM (NT): C[m,n] = sum_k A[m,k]*W[n,k], fp32 out.
// m97 structure: 128x128 tile, BK=64, 4 waves -> 64x64 each (4x4 16x16 frags).
// EPI==1: += bias[n] then softplus.
// ---------------------------------------------------------------------------
template<int EPI>
__global__ __launch_bounds__(256)
void gemm_bf16(const short* __restrict__ A, const short* __restrict__ W,
               const float* __restrict__ bias, float* __restrict__ C,
               int K, int ldc)
{
    __shared__ short As[128*64];
    __shared__ short Bs[128*64];
    const int tid = threadIdx.x;
    const int w = tid >> 6, l = tid & 63;
    const int mTile = blockIdx.y * 128, nTile = blockIdx.x * 128;
    const int wr = w >> 1, wc = w & 1;
    const int srow = l >> 3;
    const int scol = (l & 7) * 8;

    f32x4 acc[4][4];
#pragma unroll
    for (int i = 0; i < 4; ++i)
#pragma unroll
        for (int j = 0; j < 4; ++j) acc[i][j] = (f32x4)0.f;

    for (int kb = 0; kb < K; kb += 64) {
        __syncthreads();
#pragma unroll
        for (int j = 0; j < 4; ++j) {
            const int row = (j*4 + w)*8 + srow;
            __builtin_amdgcn_global_load_lds(
                (const __attribute__((address_space(1))) void*)(A + (size_t)(mTile+row)*K + kb + scol),
                (__attribute__((address_space(3))) void*)(As + row*64 + scol), 16, 0, 0);
            __builtin_amdgcn_global_load_lds(
                (const __attribute__((address_space(1))) void*)(W + (size_t)(nTile+row)*K + kb + scol),
                (__attribute__((address_space(3))) void*)(Bs + row*64 + scol), 16, 0, 0);
        }
        __syncthreads();
#pragma unroll
        for (int kk = 0; kk < 2; ++kk) {
            bf16x8 af[4], bfr[4];
#pragma unroll
            for (int i = 0; i < 4; ++i) {
                af [i] = *(const bf16x8*)&As[(wr*64 + i*16 + (l&15))*64 + kk*32 + (l>>4)*8];
                bfr[i] = *(const bf16x8*)&Bs[(wc*64 + i*16 + (l&15))*64 + kk*32 + (l>>4)*8];
            }
#pragma unroll
            for (int i = 0; i < 4; ++i)
#pragma unroll
                for (int jf = 0; jf < 4; ++jf)
                    acc[i][jf] = __builtin_amdgcn_mfma_f32_16x16x32_bf16(af[i], bfr[jf], acc[i][jf], 0, 0, 0);
        }
    }

#pragma unroll
    for (int i = 0; i < 4; ++i) {
        const int mbase = mTile + wr*64 + i*16 + (l >> 4)*4;
#pragma unroll
        for (int jf = 0; jf < 4; ++jf) {
            const int n = nTile + wc*64 + jf*16 + (l & 15);
            float bv = (EPI == 1) ? bias[n] : 0.f;
#pragma unroll
            for (int r = 0; r < 4; ++r) {
                float v = acc[i][jf][r];
                if (EPI == 1) {
                    v += bv;
                    v = fmaxf(v, 0.f) + log1pf(expf(-fabsf(v)));
                }
                C[(size_t)(mbase + r)*ldc + n] = v;
            }
        }
    }
}

// ---------------------------------------------------------------------------
// Depthwise causal conv (width 4) + bias + SiLU -> bf16 xc.
// ---------------------------------------------------------------------------
__global__ __launch_bounds__(256)
void conv_silu_kernel(const float* __restrict__ xz, const float4* __restrict__ cw,
                      const float* __restrict__ cb, short* __restrict__ xcb)
{
    const int idx = blockIdx.x * 256 + threadIdx.x;
    const int c = idx % DINNER;
    const int m = idx / DINNER;
    const int t = m & (TT - 1);
    const float4 w = cw[c];
    const size_t p = (size_t)m * (2*DINNER) + c;
    float acc = cb[c];
    if (t >= 3) {
        acc = fmaf(w.x, xz[p - (size_t)3*2*DINNER], acc);
        acc = fmaf(w.y, xz[p - (size_t)2*2*DINNER], acc);
        acc = fmaf(w.z, xz[p - (size_t)1*2*DINNER], acc);
        acc = fmaf(w.w, xz[p], acc);
    } else {
        acc = fmaf(w.w, xz[p], acc);
        if (t >= 1) acc = fmaf(w.z, xz[p - (size_t)1*2*DINNER], acc);
        if (t >= 2) acc = fmaf(w.y, xz[p - (size_t)2*2*DINNER], acc);
    }
    xcb[idx] = f2bf(acc / (1.f + __expf(-acc)));
}

// ---------------------------------------------------------------------------
// Bv[m,n] = sum_d xc[m,d]*B_w[n,d];  Cv likewise. xc in bf16.
// ---------------------------------------------------------------------------
__global__ __launch_bounds__(256)
void bc_kernel(const short* __restrict__ xcb, const float* __restrict__ Bw,
               const float* __restrict__ Cw, float* __restrict__ Bv, float* __restrict__ Cv)
{
    const int idx = blockIdx.x * 256 + threadIdx.x;
    const int m = idx >> 5;
    const int n = idx & 31;
    const float* __restrict__ w = (n < 16) ? (Bw + (size_t)n * DINNER)
                                           : (Cw + (size_t)(n - 16) * DINNER);
    const short* __restrict__ xr = xcb + (size_t)m * DINNER;
    float s = 0.f;
#pragma unroll 2
    for (int d0 = 0; d0 < DINNER; d0 += 8) {
        const short8 a = *(const short8*)&xr[d0];
        const float4 b0 = *(const float4*)&w[d0];
        const float4 b1 = *(const float4*)&w[d0+4];
        s = fmaf(bf2f(a[0]), b0.x, s); s = fmaf(bf2f(a[1]), b0.y, s);
        s = fmaf(bf2f(a[2]), b0.z, s); s = fmaf(bf2f(a[3]), b0.w, s);
        s = fmaf(bf2f(a[4]), b1.x, s); s = fmaf(bf2f(a[5]), b1.y, s);
        s = fmaf(bf2f(a[6]), b1.z, s); s = fmaf(bf2f(a[7]), b1.w, s);
    }
    if (n < 16) Bv[(size_t)m*DSTATE + n] = s;
    else        Cv[(size_t)m*DSTATE + (n - 16)] = s;
}

// ---------------------------------------------------------------------------
// Chunked scan pass 1: thread = (c,b,d), all 16 states in registers.
//   P[c][j..j+15] = prod dA, S[c][j..j+15] = local h (h_in=0), j=(b*DINNER+d)*16
// ---------------------------------------------------------------------------
__global__ __launch_bounds__(256)
void scan_pass1(const float* __restrict__ dt, const short* __restrict__ xcb,
                const float* __restrict__ Bv, const float* __restrict__ A_log,
                float* __restrict__ P, float* __restrict__ S)
{
    __shared__ float bvs[LC*DSTATE];   // 2 KB
    const int bid = blockIdx.x;
    const int tid = threadIdx.x;
    const int dblk = bid % DBLK;
    const int cb   = bid / DBLK;
    const int b    = cb & (BB-1);
    const int c    = cb >> 1;
    const int d    = dblk*256 + tid;
    const size_t m0 = (size_t)b*TT + (size_t)c*LC;

    if (tid < LC*DSTATE/4)
        *(float4*)&bvs[tid*4] = *(const float4*)&Bv[m0*DSTATE + tid*4];
    __syncthreads();

    float a[DSTATE];
#pragma unroll
    for (int n = 0; n < DSTATE; ++n) a[n] = -__expf(A_log[(size_t)d*DSTATE + n]);

    float h[DSTATE], p[DSTATE];
#pragma unroll
    for (int n = 0; n < DSTATE; ++n) { h[n] = 0.f; p[n] = 1.f; }

    const float* __restrict__ dtp = dt  + m0*DINNER + d;
    const short* __restrict__ xcp = xcb + m0*DINNER + d;
    for (int t = 0; t < LC; ++t) {
        const float dtv = dtp[(size_t)t*DINNER];
        const float xv  = bf2f(xcp[(size_t)t*DINNER]);
        const float du  = dtv * xv;
#pragma unroll
        for (int n = 0; n < DSTATE; ++n) {
            const float dA = __expf(dtv * a[n]);
            p[n] *= dA;
            h[n] = fmaf(dA, h[n], du * bvs[t*DSTATE + n]);
        }
    }
    const size_t g = (size_t)c*GROUPS + ((size_t)b*DINNER + d)*DSTATE;
#pragma unroll
    for (int q = 0; q < 4; ++q) {
        float4 hp; hp.x=h[q*4]; hp.y=h[q*4+1]; hp.z=h[q*4+2]; hp.w=h[q*4+3];
        float4 pp; pp.x=p[q*4]; pp.y=p[q*4+1]; pp.z=p[q*4+2]; pp.w=p[q*4+3];
        *(float4*)&S[g + q*4] = hp;
        *(float4*)&P[g + q*4] = pp;
    }
}

// ---------------------------------------------------------------------------
// Chunked scan pass 2: sequential combine; PH[c][j] <- h_in for chunk c.
// ---------------------------------------------------------------------------
__global__ __launch_bounds__(256)
void scan_combine(float* __restrict__ PH, const float* __restrict__ S)
{
    const int j = blockIdx.x * 256 + threadIdx.x;   // < GROUPS
    float h = 0.f;
#pragma unroll 4
    for (int c = 0; c < NC; ++c) {
        const size_t o = (size_t)c * GROUPS + j;
        const float p = PH[o];
        const float s = S[o];
        PH[o] = h;
        h = fmaf(p, h, s);
    }
}

// ---------------------------------------------------------------------------
// Chunked scan pass 3: thread = (c,b,d); from exact h_in emit
//   y = (h.C)*silu(z) + xc*D  (bf16 out). Bv/Cv staged in LDS (broadcast).
// ---------------------------------------------------------------------------
__global__ __launch_bounds__(256)
void scan_pass3(const float* __restrict__ dt, const short* __restrict__ xcb,
                const float* __restrict__ Bv, const float* __restrict__ Cv,
                const float* __restrict__ A_log, const float* __restrict__ Dp,
                const float* __restrict__ xz, const float* __restrict__ H0,
                short* __restrict__ yb)
{
    __shared__ float bvs[LC*DSTATE];   // 2 KB
    __shared__ float cvs[LC*DSTATE];   // 2 KB
    const int bid = blockIdx.x;
    const int tid = threadIdx.x;
    const int dblk = bid % DBLK;
    const int cb   = bid / DBLK;
    const int b    = cb & (BB-1);
    const int c    = cb >> 1;
    const int d    = dblk*256 + tid;
    const size_t m0 = (size_t)b*TT + (size_t)c*LC;

    if (tid < 128)
        *(float4*)&bvs[tid*4] = *(const float4*)&Bv[m0*DSTATE + tid*4];
    else
        *(float4*)&cvs[(tid-128)*4] = *(const float4*)&Cv[m0*DSTATE + (tid-128)*4];
    __syncthreads();

    float a[DSTATE];
#pragma unroll
    for (int n = 0; n < DSTATE; ++n) a[n] = -__expf(A_log[(size_t)d*DSTATE + n]);
    const float Dv = Dp[d];

    float h[DSTATE];
    const size_t g = (size_t)c*GROUPS + ((size_t)b*DINNER + d)*DSTATE;
#pragma unroll
    for (int q = 0; q < 4; ++q) {
        const float4 h4 = *(const float4*)&H0[g + q*4];
        h[q*4]=h4.x; h[q*4+1]=h4.y; h[q*4+2]=h4.z; h[q*4+3]=h4.w;
    }

    const float* __restrict__ dtp = dt  + m0*DINNER + d;
    const short* __restrict__ xcp = xcb + m0*DINNER + d;
    const float* __restrict__ zp  = xz  + m0*(2*DINNER) + DINNER + d;
    short* __restrict__ yp = yb + m0*DINNER + d;
    for (int t = 0; t < LC; ++t) {
        const float dtv = dtp[(size_t)t*DINNER];
        const float xv  = bf2f(xcp[(size_t)t*DINNER]);
        const float zv  = zp [(size_t)t*(2*DINNER)];
        const float du  = dtv * xv;
        float r = 0.f;
#pragma unroll
        for (int n = 0; n < DSTATE; ++n) {
            const float dA = __expf(dtv * a[n]);
            h[n] = fmaf(dA, h[n], du * bvs[t*DSTATE + n]);
            r = fmaf(h[n], cvs[t*DSTATE + n], r);
        }
        const float sz = zv / (1.f + __expf(-zv));
        yp[(size_t)t*DINNER] = f2bf(fmaf(r, sz, xv * Dv));
    }
}

// ---------------------------------------------------------------------------
// RMSNorm over last dim (768) of (o + x), scaled by norm_w.
// ---------------------------------------------------------------------------
__global__ __launch_bounds__(256)
void rmsnorm_kernel(const float* __restrict__ o, const float* __restrict__ x,
                    const float* __restrict__ nw, float* __restrict__ outp)
{
    const int mrow = blockIdx.x;
    const int tid  = threadIdx.x;
    const size_t base = (size_t)mrow * DMODEL;
    const int i0 = tid, i1 = tid + 256, i2 = tid + 512;
    float r0 = o[base+i0] + x[base+i0];
    float r1 = o[base+i1] + x[base+i1];
    float r2 = o[base+i2] + x[base+i2];
    float ss = r0*r0 + r1*r1 + r2*r2;
    ss += __shfl_xor(ss, 1);  ss += __shfl_xor(ss, 2);  ss += __shfl_xor(ss, 4);
    ss += __shfl_xor(ss, 8);  ss += __shfl_xor(ss, 16); ss += __shfl_xor(ss, 32);
    __shared__ float red[4];
    if ((tid & 63) == 0) red[tid >> 6] = ss;
    __syncthreads();
    const float tot = red[0] + red[1] + red[2] + red[3];
    const float sc = rsqrtf(tot * (1.f / (float)DMODEL) + 1e-6f);
    outp[base+i0] = r0 * sc * nw[i0];
    outp[base+i1] = r1 * sc * nw[i1];
    outp[base+i2] = r2 * sc * nw[i2];
}

// ---------------------------------------------------------------------------
extern "C" void kernel_launch(void* const* d_in, const int* in_sizes, int n_in,
                              void* d_out, int out_size, void* d_ws, size_t ws_size,
                              hipStream_t stream)
{
    const float* x         = (const float*)d_in[0];
    const float* in_proj_w = (const float*)d_in[1];
    const float* conv_w    = (const float*)d_in[2];
    const float* conv_b    = (const float*)d_in[3];
    const float* dt_w      = (const float*)d_in[4];
    const float* dt_b      = (const float*)d_in[5];
    const float* A_log     = (const float*)d_in[6];
    const float* B_w       = (const float*)d_in[7];
    const float* C_w       = (const float*)d_in[8];
    const float* D_param   = (const float*)d_in[9];
    const float* out_w     = (const float*)d_in[10];
    const float* norm_w    = (const float*)d_in[11];
    float* out = (float*)d_out;

    // ---- workspace layout: fp32 region then bf16 region ----
    float* ws  = (float*)d_ws;
    float* xz  = ws;                               // [4096][3072]  12,582,912 f
    float* dtb = xz  + (size_t)MM * 2*DINNER;      // [4096][1536]   6,291,456 f
    float* Bv  = dtb + (size_t)MM * DINNER;        // [4096][16]        65,536 f
    float* Cv  = Bv  + (size_t)MM * DSTATE;        // [4096][16]        65,536 f
    float* Pa  = Cv  + (size_t)MM * DSTATE;        // [NC][GROUPS]   3,145,728 f
    float* Sa  = Pa  + (size_t)NC * GROUPS;        // [NC][GROUPS]   3,145,728 f
    short* bfb = (short*)(Sa + (size_t)NC * GROUPS);
    short* xb  = bfb;                              // x bf16        3,145,728 s
    short* wib = xb  + (size_t)S0;                 // in_proj bf16  2,359,296 s
    short* wdb = wib + (size_t)S1;                 // dt_w bf16     2,359,296 s
    short* wob = wdb + (size_t)S2;                 // out_w bf16    1,179,648 s
    short* xcb = wob + (size_t)S3;                 // xc bf16       6,291,456 s
    short* yb  = xcb + (size_t)MM * DINNER;        // y bf16        6,291,456 s
    float* o   = xz;                               // out-proj result reuses xz

    // 0) pack fp32 -> bf16 (x + 3 weight matrices)
    cvt_pack<<<TOTC/8/256, 256, 0, stream>>>(x, in_proj_w, dt_w, out_w, xb, wib, wdb, wob);
    // 1) xz = x @ in_proj_w^T          (4096 x 3072 x 768, bf16 MFMA)
    gemm_bf16<0><<<dim3(2*DINNER/128, MM/128), 256, 0, stream>>>(xb, wib, nullptr, xz, DMODEL, 2*DINNER);
    // 2) xc = silu(causal_conv(x_proj) + conv_b)  -> bf16
    conv_silu_kernel<<<(MM*DINNER)/256, 256, 0, stream>>>(xz, (const float4*)conv_w, conv_b, xcb);
    // 3) dt = softplus(xc @ dt_w^T + dt_b)   (4096 x 1536 x 1536, bf16 MFMA)
    gemm_bf16<1><<<dim3(DINNER/128, MM/128), 256, 0, stream>>>(xcb, wdb, dt_b, dtb, DINNER, DINNER);
    // 3b) Bv, Cv = xc @ {B_w,C_w}^T
    bc_kernel<<<(MM*32)/256, 256, 0, stream>>>(xcb, B_w, C_w, Bv, Cv);
    // 4) chunked selective scan (thread = channel, 16 states in regs)
    scan_pass1<<<NC*BB*DBLK, 256, 0, stream>>>(dtb, xcb, Bv, A_log, Pa, Sa);
    scan_combine<<<GROUPS/256, 256, 0, stream>>>(Pa, Sa);
    scan_pass3<<<NC*BB*DBLK, 256, 0, stream>>>(dtb, xcb, Bv, Cv, A_log, D_param, xz, Pa, yb);
    // 5) o = y @ out_w^T               (4096 x 768 x 1536, bf16 MFMA)
    gemm_bf16<0><<<dim3(DMODEL/128, MM/128), 256, 0, stream>>>(yb, wob, nullptr, o, DINNER, DMODEL);
    // 6) out = rmsnorm(o + x) * norm_w
    rmsnorm_kernel<<<MM, 256, 0, stream>>>(o, x, norm_w, out);
}

// Round 5
// 311.697 us; speedup vs baseline: 5.0586x; 1.0976x over previous
//
#include <hip/hip_runtime.h>

// SelectiveSSM (Mamba block): B=2, T=2048, D_MODEL=768, D_INNER=1536, D_STATE=16, D_CONV=4
// R5: GEMM K-loop -> double-buffered single-sync pipeline (stage t+1 before compute t,
//     drain covered by MFMA work). Out-proj GEMM split-K=2 in one dispatch (grid.z).
// Scan (R4 structure), conv, bc unchanged.

#define BB 2
#define TT 2048
#define DMODEL 768
#define DINNER 1536
#define DSTATE 16
#define MM (BB*TT)   // 4096 rows

#define NC 64
#define LC (TT/NC)   // 32 steps per chunk
#define GROUPS (BB*DINNER*DSTATE)   // 49152
#define DBLK (DINNER/256)           // 6 blocks per (c,b)

typedef __attribute__((ext_vector_type(8))) short bf16x8;
typedef __attribute__((ext_vector_type(4))) float f32x4;
typedef __attribute__((ext_vector_type(8))) short short8;

__device__ inline float bf2f(short u) {
    union { unsigned int i; float f; } v;
    v.i = ((unsigned int)(unsigned short)u) << 16;
    return v.f;
}
__device__ inline short f2bf(float f) {   // round-to-nearest-even
    unsigned int u = __float_as_uint(f);
    u = (u + 0x7fffu + ((u >> 16) & 1u)) >> 16;
    return (short)u;
}

// ---------------------------------------------------------------------------
// Fused fp32->bf16 pack: x, in_proj_w, dt_w, out_w. 8 elems/thread.
// ---------------------------------------------------------------------------
#define S0 (MM*DMODEL)          // x        3,145,728
#define S1 (2*DINNER*DMODEL)    // in_proj  2,359,296
#define S2 (DINNER*DINNER)      // dt_w     2,359,296
#define S3 (DMODEL*DINNER)      // out_w    1,179,648
#define TOTC (S0+S1+S2+S3)      //          9,043,968

__global__ __launch_bounds__(256)
void cvt_pack(const float* __restrict__ x, const float* __restrict__ w1,
              const float* __restrict__ w2, const float* __restrict__ w3,
              short* __restrict__ xb, short* __restrict__ b1,
              short* __restrict__ b2, short* __restrict__ b3)
{
    const size_t i8 = ((size_t)blockIdx.x * 256 + threadIdx.x) * 8;
    const float* src; short* dst; size_t off;
    if (i8 < S0)            { src = x;  dst = xb; off = i8; }
    else if (i8 < S0+S1)    { src = w1; dst = b1; off = i8 - S0; }
    else if (i8 < S0+S1+S2) { src = w2; dst = b2; off = i8 - (S0+S1); }
    else                    { src = w3; dst = b3; off = i8 - (S0+S1+S2); }
    const float4 a = *(const float4*)(src + off);
    const float4 b = *(const float4*)(src + off + 4);
    short8 o;
    o[0]=f2bf(a.x); o[1]=f2bf(a.y); o[2]=f2bf(a.z); o[3]=f2bf(a.w);
    o[4]=f2bf(b.x); o[5]=f2bf(b.y); o[6]=f2bf(b.z); o[7]=f2bf(b.w);
    *(short8*)(dst + off) = o;
}

// ---------------------------------------------------------------------------
// bf16 MFMA GEMM (NT): C[m,n] = sum_k A[m,k]*W[n,k], fp32 out.
// 128x128 tile, BK=64, 4 waves -> 64x64 each. Double-buffered LDS:
//   {stage(buf^1, t+1); compute(buf, t); __syncthreads()}  — one sync/K-step,
//   drain of next-tile global_load_lds covered by ds_read+MFMA of current.
// lda = row stride of A and W (decoupled from K extent for split-K).
// blockIdx.z selects a K-slice; C += z*splitStride (splitStride in elems).
// EPI==1: += bias[n] then softplus.
// ---------------------------------------------------------------------------
template<int EPI>
__global__ __launch_bounds__(256)
void gemm_bf16(const short* __restrict__ A, const short* __restrict__ W,
               const float* __restrict__ bias, float* __restrict__ C,
               int K, int lda, int ldc, size_t splitStride)
{
    __shared__ short As[2][128*64];
    __shared__ short Bs[2][128*64];
    const int tid = threadIdx.x;
    const int w = tid >> 6, l = tid & 63;
    const int mTile = blockIdx.y * 128, nTile = blockIdx.x * 128;
    const int wr = w >> 1, wc = w & 1;
    const int srow = l >> 3;
    const int scol = (l & 7) * 8;

    A += (size_t)blockIdx.z * K;
    W += (size_t)blockIdx.z * K;
    C += (size_t)blockIdx.z * splitStride;

    f32x4 acc[4][4];
#pragma unroll
    for (int i = 0; i < 4; ++i)
#pragma unroll
        for (int j = 0; j < 4; ++j) acc[i][j] = (f32x4)0.f;

    const short* __restrict__ Ab = A + (size_t)mTile * lda + scol;
    const short* __restrict__ Wb = W + (size_t)nTile * lda + scol;

    auto stage = [&](int bsel, int kb) {
#pragma unroll
        for (int j = 0; j < 4; ++j) {
            const int row = (j*4 + w)*8 + srow;
            __builtin_amdgcn_global_load_lds(
                (const __attribute__((address_space(1))) void*)(Ab + (size_t)row*lda + kb),
                (__attribute__((address_space(3))) void*)(&As[bsel][row*64 + scol]), 16, 0, 0);
            __builtin_amdgcn_global_load_lds(
                (const __attribute__((address_space(1))) void*)(Wb + (size_t)row*lda + kb),
                (__attribute__((address_space(3))) void*)(&Bs[bsel][row*64 + scol]), 16, 0, 0);
        }
    };

    auto compute = [&](int bsel) {
#pragma unroll
        for (int kk = 0; kk < 2; ++kk) {
            bf16x8 af[4], bfr[4];
#pragma unroll
            for (int i = 0; i < 4; ++i) {
                af [i] = *(const bf16x8*)&As[bsel][(wr*64 + i*16 + (l&15))*64 + kk*32 + (l>>4)*8];
                bfr[i] = *(const bf16x8*)&Bs[bsel][(wc*64 + i*16 + (l&15))*64 + kk*32 + (l>>4)*8];
            }
#pragma unroll
            for (int i = 0; i < 4; ++i)
#pragma unroll
                for (int jf = 0; jf < 4; ++jf)
                    acc[i][jf] = __builtin_amdgcn_mfma_f32_16x16x32_bf16(af[i], bfr[jf], acc[i][jf], 0, 0, 0);
        }
    };

    const int nk = K / 64;      // 12 or 24 (always even)
    stage(0, 0);
    __syncthreads();
    for (int t = 0; t < nk; t += 2) {
        if (t + 1 < nk) stage(1, (t+1)*64);
        compute(0);
        __syncthreads();
        if (t + 2 < nk) stage(0, (t+2)*64);
        compute(1);
        __syncthreads();
    }

    // C/D layout (m89-verified): col = lane&15, row = (lane>>4)*4 + reg
#pragma unroll
    for (int i = 0; i < 4; ++i) {
        const int mbase = mTile + wr*64 + i*16 + (l >> 4)*4;
#pragma unroll
        for (int jf = 0; jf < 4; ++jf) {
            const int n = nTile + wc*64 + jf*16 + (l & 15);
            float bv = (EPI == 1) ? bias[n] : 0.f;
#pragma unroll
            for (int r = 0; r < 4; ++r) {
                float v = acc[i][jf][r];
                if (EPI == 1) {
                    v += bv;
                    v = fmaxf(v, 0.f) + log1pf(expf(-fabsf(v)));
                }
                C[(size_t)(mbase + r)*ldc + n] = v;
            }
        }
    }
}

// ---------------------------------------------------------------------------
// Depthwise causal conv (width 4) + bias + SiLU -> bf16 xc.
// ---------------------------------------------------------------------------
__global__ __launch_bounds__(256)
void conv_silu_kernel(const float* __restrict__ xz, const float4* __restrict__ cw,
                      const float* __restrict__ cb, short* __restrict__ xcb)
{
    const int idx = blockIdx.x * 256 + threadIdx.x;
    const int c = idx % DINNER;
    const int m = idx / DINNER;
    const int t = m & (TT - 1);
    const float4 w = cw[c];
    const size_t p = (size_t)m * (2*DINNER) + c;
    float acc = cb[c];
    if (t >= 3) {
        acc = fmaf(w.x, xz[p - (size_t)3*2*DINNER], acc);
        acc = fmaf(w.y, xz[p - (size_t)2*2*DINNER], acc);
        acc = fmaf(w.z, xz[p - (size_t)1*2*DINNER], acc);
        acc = fmaf(w.w, xz[p], acc);
    } else {
        acc = fmaf(w.w, xz[p], acc);
        if (t >= 1) acc = fmaf(w.z, xz[p - (size_t)1*2*DINNER], acc);
        if (t >= 2) acc = fmaf(w.y, xz[p - (size_t)2*2*DINNER], acc);
    }
    xcb[idx] = f2bf(acc / (1.f + __expf(-acc)));
}

// ---------------------------------------------------------------------------
// Bv[m,n] = sum_d xc[m,d]*B_w[n,d];  Cv likewise. xc in bf16.
// ---------------------------------------------------------------------------
__global__ __launch_bounds__(256)
void bc_kernel(const short* __restrict__ xcb, const float* __restrict__ Bw,
               const float* __restrict__ Cw, float* __restrict__ Bv, float* __restrict__ Cv)
{
    const int idx = blockIdx.x * 256 + threadIdx.x;
    const int m = idx >> 5;
    const int n = idx & 31;
    const float* __restrict__ w = (n < 16) ? (Bw + (size_t)n * DINNER)
                                           : (Cw + (size_t)(n - 16) * DINNER);
    const short* __restrict__ xr = xcb + (size_t)m * DINNER;
    float s = 0.f;
#pragma unroll 2
    for (int d0 = 0; d0 < DINNER; d0 += 8) {
        const short8 a = *(const short8*)&xr[d0];
        const float4 b0 = *(const float4*)&w[d0];
        const float4 b1 = *(const float4*)&w[d0+4];
        s = fmaf(bf2f(a[0]), b0.x, s); s = fmaf(bf2f(a[1]), b0.y, s);
        s = fmaf(bf2f(a[2]), b0.z, s); s = fmaf(bf2f(a[3]), b0.w, s);
        s = fmaf(bf2f(a[4]), b1.x, s); s = fmaf(bf2f(a[5]), b1.y, s);
        s = fmaf(bf2f(a[6]), b1.z, s); s = fmaf(bf2f(a[7]), b1.w, s);
    }
    if (n < 16) Bv[(size_t)m*DSTATE + n] = s;
    else        Cv[(size_t)m*DSTATE + (n - 16)] = s;
}

// ---------------------------------------------------------------------------
// Chunked scan pass 1: thread = (c,b,d), all 16 states in registers.
// ---------------------------------------------------------------------------
__global__ __launch_bounds__(256)
void scan_pass1(const float* __restrict__ dt, const short* __restrict__ xcb,
                const float* __restrict__ Bv, const float* __restrict__ A_log,
                float* __restrict__ P, float* __restrict__ S)
{
    __shared__ float bvs[LC*DSTATE];   // 2 KB
    const int bid = blockIdx.x;
    const int tid = threadIdx.x;
    const int dblk = bid % DBLK;
    const int cb   = bid / DBLK;
    const int b    = cb & (BB-1);
    const int c    = cb >> 1;
    const int d    = dblk*256 + tid;
    const size_t m0 = (size_t)b*TT + (size_t)c*LC;

    if (tid < LC*DSTATE/4)
        *(float4*)&bvs[tid*4] = *(const float4*)&Bv[m0*DSTATE + tid*4];
    __syncthreads();

    float a[DSTATE];
#pragma unroll
    for (int n = 0; n < DSTATE; ++n) a[n] = -__expf(A_log[(size_t)d*DSTATE + n]);

    float h[DSTATE], p[DSTATE];
#pragma unroll
    for (int n = 0; n < DSTATE; ++n) { h[n] = 0.f; p[n] = 1.f; }

    const float* __restrict__ dtp = dt  + m0*DINNER + d;
    const short* __restrict__ xcp = xcb + m0*DINNER + d;
    for (int t = 0; t < LC; ++t) {
        const float dtv = dtp[(size_t)t*DINNER];
        const float xv  = bf2f(xcp[(size_t)t*DINNER]);
        const float du  = dtv * xv;
#pragma unroll
        for (int n = 0; n < DSTATE; ++n) {
            const float dA = __expf(dtv * a[n]);
            p[n] *= dA;
            h[n] = fmaf(dA, h[n], du * bvs[t*DSTATE + n]);
        }
    }
    const size_t g = (size_t)c*GROUPS + ((size_t)b*DINNER + d)*DSTATE;
#pragma unroll
    for (int q = 0; q < 4; ++q) {
        float4 hp; hp.x=h[q*4]; hp.y=h[q*4+1]; hp.z=h[q*4+2]; hp.w=h[q*4+3];
        float4 pp; pp.x=p[q*4]; pp.y=p[q*4+1]; pp.z=p[q*4+2]; pp.w=p[q*4+3];
        *(float4*)&S[g + q*4] = hp;
        *(float4*)&P[g + q*4] = pp;
    }
}

// ---------------------------------------------------------------------------
// Chunked scan pass 2: sequential combine; PH[c][j] <- h_in for chunk c.
// ---------------------------------------------------------------------------
__global__ __launch_bounds__(256)
void scan_combine(float* __restrict__ PH, const float* __restrict__ S)
{
    const int j = blockIdx.x * 256 + threadIdx.x;   // < GROUPS
    float h = 0.f;
#pragma unroll 4
    for (int c = 0; c < NC; ++c) {
        const size_t o = (size_t)c * GROUPS + j;
        const float p = PH[o];
        const float s = S[o];
        PH[o] = h;
        h = fmaf(p, h, s);
    }
}

// ---------------------------------------------------------------------------
// Chunked scan pass 3: thread = (c,b,d); from exact h_in emit
//   y = (h.C)*silu(z) + xc*D  (bf16 out). Bv/Cv staged in LDS (broadcast).
// ---------------------------------------------------------------------------
__global__ __launch_bounds__(256)
void scan_pass3(const float* __restrict__ dt, const short* __restrict__ xcb,
                const float* __restrict__ Bv, const float* __restrict__ Cv,
                const float* __restrict__ A_log, const float* __restrict__ Dp,
                const float* __restrict__ xz, const float* __restrict__ H0,
                short* __restrict__ yb)
{
    __shared__ float bvs[LC*DSTATE];   // 2 KB
    __shared__ float cvs[LC*DSTATE];   // 2 KB
    const int bid = blockIdx.x;
    const int tid = threadIdx.x;
    const int dblk = bid % DBLK;
    const int cb   = bid / DBLK;
    const int b    = cb & (BB-1);
    const int c    = cb >> 1;
    const int d    = dblk*256 + tid;
    const size_t m0 = (size_t)b*TT + (size_t)c*LC;

    if (tid < 128)
        *(float4*)&bvs[tid*4] = *(const float4*)&Bv[m0*DSTATE + tid*4];
    else
        *(float4*)&cvs[(tid-128)*4] = *(const float4*)&Cv[m0*DSTATE + (tid-128)*4];
    __syncthreads();

    float a[DSTATE];
#pragma unroll
    for (int n = 0; n < DSTATE; ++n) a[n] = -__expf(A_log[(size_t)d*DSTATE + n]);
    const float Dv = Dp[d];

    float h[DSTATE];
    const size_t g = (size_t)c*GROUPS + ((size_t)b*DINNER + d)*DSTATE;
#pragma unroll
    for (int q = 0; q < 4; ++q) {
        const float4 h4 = *(const float4*)&H0[g + q*4];
        h[q*4]=h4.x; h[q*4+1]=h4.y; h[q*4+2]=h4.z; h[q*4+3]=h4.w;
    }

    const float* __restrict__ dtp = dt  + m0*DINNER + d;
    const short* __restrict__ xcp = xcb + m0*DINNER + d;
    const float* __restrict__ zp  = xz  + m0*(2*DINNER) + DINNER + d;
    short* __restrict__ yp = yb + m0*DINNER + d;
    for (int t = 0; t < LC; ++t) {
        const float dtv = dtp[(size_t)t*DINNER];
        const float xv  = bf2f(xcp[(size_t)t*DINNER]);
        const float zv  = zp [(size_t)t*(2*DINNER)];
        const float du  = dtv * xv;
        float r = 0.f;
#pragma unroll
        for (int n = 0; n < DSTATE; ++n) {
            const float dA = __expf(dtv * a[n]);
            h[n] = fmaf(dA, h[n], du * bvs[t*DSTATE + n]);
            r = fmaf(h[n], cvs[t*DSTATE + n], r);
        }
        const float sz = zv / (1.f + __expf(-zv));
        yp[(size_t)t*DINNER] = f2bf(fmaf(r, sz, xv * Dv));
    }
}

// ---------------------------------------------------------------------------
// RMSNorm over last dim (768) of (o1 + o2 + x), scaled by norm_w.
// ---------------------------------------------------------------------------
__global__ __launch_bounds__(256)
void rmsnorm_kernel(const float* __restrict__ o1, const float* __restrict__ o2,
                    const float* __restrict__ x, const float* __restrict__ nw,
                    float* __restrict__ outp)
{
    const int mrow = blockIdx.x;
    const int tid  = threadIdx.x;
    const size_t base = (size_t)mrow * DMODEL;
    const int i0 = tid, i1 = tid + 256, i2 = tid + 512;
    float r0 = o1[base+i0] + o2[base+i0] + x[base+i0];
    float r1 = o1[base+i1] + o2[base+i1] + x[base+i1];
    float r2 = o1[base+i2] + o2[base+i2] + x[base+i2];
    float ss = r0*r0 + r1*r1 + r2*r2;
    ss += __shfl_xor(ss, 1);  ss += __shfl_xor(ss, 2);  ss += __shfl_xor(ss, 4);
    ss += __shfl_xor(ss, 8);  ss += __shfl_xor(ss, 16); ss += __shfl_xor(ss, 32);
    __shared__ float red[4];
    if ((tid & 63) == 0) red[tid >> 6] = ss;
    __syncthreads();
    const float tot = red[0] + red[1] + red[2] + red[3];
    const float sc = rsqrtf(tot * (1.f / (float)DMODEL) + 1e-6f);
    outp[base+i0] = r0 * sc * nw[i0];
    outp[base+i1] = r1 * sc * nw[i1];
    outp[base+i2] = r2 * sc * nw[i2];
}

// ---------------------------------------------------------------------------
extern "C" void kernel_launch(void* const* d_in, const int* in_sizes, int n_in,
                              void* d_out, int out_size, void* d_ws, size_t ws_size,
                              hipStream_t stream)
{
    const float* x         = (const float*)d_in[0];
    const float* in_proj_w = (const float*)d_in[1];
    const float* conv_w    = (const float*)d_in[2];
    const float* conv_b    = (const float*)d_in[3];
    const float* dt_w      = (const float*)d_in[4];
    const float* dt_b      = (const float*)d_in[5];
    const float* A_log     = (const float*)d_in[6];
    const float* B_w       = (const float*)d_in[7];
    const float* C_w       = (const float*)d_in[8];
    const float* D_param   = (const float*)d_in[9];
    const float* out_w     = (const float*)d_in[10];
    const float* norm_w    = (const float*)d_in[11];
    float* out = (float*)d_out;

    // ---- workspace layout: fp32 region then bf16 region ----
    float* ws  = (float*)d_ws;
    float* xz  = ws;                               // [4096][3072]  12,582,912 f
    float* dtb = xz  + (size_t)MM * 2*DINNER;      // [4096][1536]   6,291,456 f
    float* Bv  = dtb + (size_t)MM * DINNER;        // [4096][16]        65,536 f
    float* Cv  = Bv  + (size_t)MM * DSTATE;        // [4096][16]        65,536 f
    float* Pa  = Cv  + (size_t)MM * DSTATE;        // [NC][GROUPS]   3,145,728 f
    float* Sa  = Pa  + (size_t)NC * GROUPS;        // [NC][GROUPS]   3,145,728 f
    short* bfb = (short*)(Sa + (size_t)NC * GROUPS);
    short* xb  = bfb;                              // x bf16        3,145,728 s
    short* wib = xb  + (size_t)S0;                 // in_proj bf16  2,359,296 s
    short* wdb = wib + (size_t)S1;                 // dt_w bf16     2,359,296 s
    short* wob = wdb + (size_t)S2;                 // out_w bf16    1,179,648 s
    short* xcb = wob + (size_t)S3;                 // xc bf16       6,291,456 s
    short* yb  = xcb + (size_t)MM * DINNER;        // y bf16        6,291,456 s
    // out-proj split-K partials overlay Pa/Sa (dead after pass3/combine):
    float* o1  = Pa;                               // [4096][768]   3,145,728 f
    float* o2  = Pa + (size_t)MM * DMODEL;         // [4096][768]   (= Sa)

    // 0) pack fp32 -> bf16 (x + 3 weight matrices)
    cvt_pack<<<TOTC/8/256, 256, 0, stream>>>(x, in_proj_w, dt_w, out_w, xb, wib, wdb, wob);
    // 1) xz = x @ in_proj_w^T          (4096 x 3072 x 768, bf16 MFMA)
    gemm_bf16<0><<<dim3(2*DINNER/128, MM/128), 256, 0, stream>>>(xb, wib, nullptr, xz, DMODEL, DMODEL, 2*DINNER, 0);
    // 2) xc = silu(causal_conv(x_proj) + conv_b)  -> bf16
    conv_silu_kernel<<<(MM*DINNER)/256, 256, 0, stream>>>(xz, (const float4*)conv_w, conv_b, xcb);
    // 3) dt = softplus(xc @ dt_w^T + dt_b)   (4096 x 1536 x 1536, bf16 MFMA)
    gemm_bf16<1><<<dim3(DINNER/128, MM/128), 256, 0, stream>>>(xcb, wdb, dt_b, dtb, DINNER, DINNER, DINNER, 0);
    // 3b) Bv, Cv = xc @ {B_w,C_w}^T
    bc_kernel<<<(MM*32)/256, 256, 0, stream>>>(xcb, B_w, C_w, Bv, Cv);
    // 4) chunked selective scan (thread = channel, 16 states in regs)
    scan_pass1<<<NC*BB*DBLK, 256, 0, stream>>>(dtb, xcb, Bv, A_log, Pa, Sa);
    scan_combine<<<GROUPS/256, 256, 0, stream>>>(Pa, Sa);
    scan_pass3<<<NC*BB*DBLK, 256, 0, stream>>>(dtb, xcb, Bv, Cv, A_log, D_param, xz, Pa, yb);
    // 5) o1/o2 = y @ out_w^T split-K   (4096 x 768 x 768 each, one dispatch, grid.z=2)
    gemm_bf16<0><<<dim3(DMODEL/128, MM/128, 2), 256, 0, stream>>>(yb, wob, nullptr, o1, DINNER/2, DINNER, DMODEL, (size_t)MM*DMODEL);
    // 6) out = rmsnorm(o1 + o2 + x) * norm_w
    rmsnorm_kernel<<<MM, 256, 0, stream>>>(o1, o2, x, norm_w, out);
}